// Round 18
// baseline (201.485 us; speedup 1.0000x reference)
//
#include <hip/hip_runtime.h>
#include <hip/hip_bf16.h>
#include <hip/hip_fp16.h>

#define N_NODES 20000
#define N_EDGES 640000
#define N_GRAPHS 256
#define NBUCK 313                    // ceil(20000/64) buckets of 64 dsts
#define NC 160                       // binC blocks per branch
#define EPC 4000                     // edges per binC block (160*4000 = 640000)
#define DCAP 2560                    // per-bucket region capacity (mean 2045 + 11 sigma)
#define CURP 16                      // bcur padding: 16 ints = 64B per bucket
#define STAGEN ((size_t)NBUCK*DCAP)  // 801,280 records per branch
#define LOG2E 1.44269504f

typedef short bf16v __attribute__((ext_vector_type(8)));   // 8 bf16 (4 VGPRs)
typedef float f32x4 __attribute__((ext_vector_type(4)));
typedef float f32x2 __attribute__((ext_vector_type(2)));

__device__ __forceinline__ float leaky02(float x){ return x > 0.f ? x : 0.2f*x; }
__device__ __forceinline__ float eluf(float x){ return x > 0.f ? x : (__expf(x) - 1.f); }
__device__ __forceinline__ unsigned short f2bf(float x){
  __hip_bfloat16 t = __float2bfloat16(x);
  return *reinterpret_cast<unsigned short*>(&t);
}
__device__ __forceinline__ float bflo(unsigned int u){ return __uint_as_float(u << 16); }
__device__ __forceinline__ float bfhi(unsigned int u){ return __uint_as_float(u & 0xffff0000u); }
__device__ __forceinline__ float bfs(unsigned short u){ return __uint_as_float(((unsigned)u) << 16); }
__device__ __forceinline__ void pkfma(f32x2& acc, f32x2 a, f32x2 b){
  asm volatile("v_pk_fma_f32 %0, %1, %2, %0" : "+v"(acc) : "v"(a), "v"(b));
}

// ---------- setup: bucket cursors + graph bounds + prep_c ----------
__global__ __launch_bounds__(512) void setup_kernel(
    const int* __restrict__ bat0, const int* __restrict__ bat1,
    const float* __restrict__ We1, const float* __restrict__ ae1,
    const float* __restrict__ We2, const float* __restrict__ ae2,
    const float* __restrict__ We3, const float* __restrict__ ae3,
    int* __restrict__ bcur, int* __restrict__ gb, float* __restrict__ scal)
{
  int b = blockIdx.x;
  int tid = threadIdx.x;
  if (tid < NBUCK) bcur[((size_t)b*NBUCK + tid)*CURP] = tid*DCAP;
  {
    const int* batch = b ? bat1 : bat0;
    int* gbb = gb + b*257;
    if (tid <= N_GRAPHS){
      int g = tid, lo = 0, hi = N_NODES;
      while (lo < hi){ int mid = (lo+hi) >> 1; if (batch[mid] < g) lo = mid+1; else hi = mid; }
      gbb[g] = lo;
    }
  }
  if (b == 0){
    int wv = tid >> 6, lane = tid & 63;
    if (wv < 3){
      const float* We = wv==0 ? We1 : (wv==1 ? We2 : We3);
      const float* ae = wv==0 ? ae1 : (wv==1 ? ae2 : ae3);
      int F = (wv==2) ? 64 : 128;
      float s = 0.f;
      for (int i = lane; i < F; i += 64) s += We[i]*ae[i];
      for (int o = 32; o; o >>= 1) s += __shfl_down(s, o);
      if (lane == 0) scal[2+wv] = s;
    }
  }
}

// ---------- binC: histogram-then-place LDS binning into padded regions + ec partials ----------
__global__ __launch_bounds__(256) void binC_kernel(
    const int* __restrict__ ei0, const int* __restrict__ ei1,
    const float* __restrict__ ec0, const float* __restrict__ ec1,
    int* __restrict__ bcur, uint2* __restrict__ stage, float* __restrict__ part)
{
  int b = blockIdx.y;
  const int* srcp = (b ? ei1 : ei0);
  const int* dstp = srcp + N_EDGES;
  const float* ec = b ? ec1 : ec0;
  int* bcurb = bcur + (size_t)b*NBUCK*CURP;
  uint2* stageb = stage + (size_t)b*STAGEN;
  __shared__ uint2 recs[EPC];
  __shared__ int hist[NBUCK], rbase[NBUCK], rcur[NBUCK];
  int tid = threadIdx.x;
  for (int j = tid; j < NBUCK; j += 256){ hist[j] = 0; rcur[j] = 0; }
  __syncthreads();
  int e0 = blockIdx.x*EPC;
  float v = 0.f;
  for (int r = tid; r < EPC; r += 256){
    int i = e0 + r;
    int d = dstp[i];
    int bk = d >> 6;
    uint2 rec;
    rec.x = (unsigned)srcp[i] | ((unsigned)(d & 63) << 16);
    float e = ec[i];
    v += e;
    rec.y = ((unsigned)f2bf(e) << 16) | (unsigned)bk;
    recs[r] = rec;
    atomicAdd(&hist[bk], 1);
  }
  __syncthreads();
  for (int j = tid; j < NBUCK; j += 256){
    int h = hist[j];
    rbase[j] = h ? atomicAdd(&bcurb[j*CURP], h) : 0;
  }
  __syncthreads();
  for (int r = tid; r < EPC; r += 256){
    uint2 rc = recs[r];
    int bk = (int)(rc.y & 0xFFFFu);
    int p = rbase[bk] + atomicAdd(&rcur[bk], 1);
    if (p < (bk + 1)*DCAP) stageb[p] = rc;   // overflow clamp (11-sigma margin)
  }
  for (int o = 32; o; o >>= 1) v += __shfl_down(v, o);
  __shared__ float wr[4];
  int lane = tid & 63, wv = tid >> 6;
  if (lane == 0) wr[wv] = v;
  __syncthreads();
  if (tid == 0) part[b*NC + blockIdx.x] = wr[0]+wr[1]+wr[2]+wr[3];
}

// ---------- binD: per-bucket counting sort -> padded CSR + int2 rowp2 (+ ec total in g==0) ----------
__global__ __launch_bounds__(256) void binD_kernel(
    const uint2* __restrict__ stage, const int* __restrict__ bcur,
    const float* __restrict__ part,
    unsigned* __restrict__ final_, int2* __restrict__ rowp2, float* __restrict__ scal)
{
  int b = blockIdx.y;
  int g = blockIdx.x;
  int tid = threadIdx.x;
  if (g == 0){
    float s = 0.f;
    for (int i = tid; i < NC; i += 256) s += part[b*NC + i];
    for (int o = 32; o; o >>= 1) s += __shfl_down(s, o);
    __shared__ float fr[4];
    if ((tid & 63) == 0) fr[tid >> 6] = s;
    __syncthreads();
    if (tid == 0) scal[b] = fr[0]+fr[1]+fr[2]+fr[3];
  }
  const uint2* stageb = stage + (size_t)b*STAGEN;
  unsigned* finb = final_ + (size_t)b*STAGEN;
  int2* rowb = rowp2 + (size_t)b*N_NODES;
  int cb = g*DCAP;
  int n = min(bcur[((size_t)b*NBUCK + g)*CURP] - cb, DCAP);
  __shared__ uint2 recs[DCAP];
  __shared__ int cnt64[64], cur64[64], off64[64];
  if (tid < 64) cnt64[tid] = 0;
  __syncthreads();
  for (int r = tid; r < n; r += 256){
    uint2 rc = stageb[cb + r];
    recs[r] = rc;
    atomicAdd(&cnt64[(rc.x >> 16) & 63], 1);
  }
  __syncthreads();
  if (tid == 0){
    int acc = 0;
    for (int dl = 0; dl < 64; ++dl){
      off64[dl] = acc; cur64[dl] = acc; acc += cnt64[dl];
    }
  }
  __syncthreads();
  int nd = min(64, N_NODES - g*64);
  if (tid < nd)
    rowb[g*64 + tid] = make_int2(cb + off64[tid], cb + off64[tid] + cnt64[tid]);
  for (int r = tid; r < n; r += 256){
    uint2 rc = recs[r];
    int dl = (rc.x >> 16) & 63;
    int p = atomicAdd(&cur64[dl], 1);
    finb[cb + p] = (rc.y & 0xFFFF0000u) | (rc.x & 0xFFFFu);
  }
}

// ---------- layer 1: K=7 scalar GEMM + att dots (prescaled), lo/hi bf16 halves out ----------
template<int K, int F>
__global__ __launch_bounds__(256) void node_linear1_kernel(
    const float* __restrict__ x0, const float* __restrict__ x1,
    const float* __restrict__ W,
    const float* __restrict__ atts, const float* __restrict__ attd,
    unsigned short* __restrict__ loAll, unsigned short* __restrict__ hiAll,
    float* __restrict__ aSAll, float* __restrict__ aDAll)
{
  int b = blockIdx.y;
  const float* x = b ? x1 : x0;
  unsigned short* lo = loAll + (size_t)b*N_NODES*64;
  unsigned short* hi = hiAll + (size_t)b*N_NODES*64;
  float* a_s = aSAll + b*N_NODES;
  float* a_d = aDAll + b*N_NODES;
  constexpr int ROWS = 256 / F; // 2
  __shared__ float Wl[K*F];
  __shared__ float xl[ROWS*K];
  __shared__ float swv[4], dwv[4];
  int tid = threadIdx.x;
  for (int i = tid; i < K*F; i += 256) Wl[i] = W[i];
  int f = tid % F;
  int lr = tid / F;
  float vs = atts[f], vd = attd[f];
  const int ntiles = (N_NODES + ROWS - 1)/ROWS;
  for (int t = blockIdx.x; t < ntiles; t += gridDim.x){
    int r0 = t*ROWS;
    __syncthreads();
    for (int i = tid; i < ROWS*K; i += 256){
      int r = i / K, k = i % K;
      int row = r0 + r;
      xl[i] = (row < N_NODES) ? x[row*K + k] : 0.f;
    }
    __syncthreads();
    float acc = 0.f;
    #pragma unroll
    for (int k = 0; k < K; ++k) acc += xl[lr*K + k] * Wl[k*F + f];
    int row = r0 + lr;
    if (row < N_NODES){
      if (f < 64) lo[(size_t)row*64 + f] = f2bf(acc);
      else        hi[(size_t)row*64 + f - 64] = f2bf(acc);
    }
    float s = acc*vs, d = acc*vd;
    #pragma unroll
    for (int o = 32; o; o >>= 1){ s += __shfl_down(s, o); d += __shfl_down(d, o); }
    int wv = tid >> 6;
    if ((tid & 63) == 0){ swv[wv] = s; dwv[wv] = d; }
    __syncthreads();
    if (f == 0 && row < N_NODES){
      a_s[row] = (swv[2*lr] + swv[2*lr+1])*LOG2E;
      a_d[row] = (dwv[2*lr] + dwv[2*lr+1])*LOG2E;
    }
  }
}

// ---------- layers 2/3: MFMA GEMM (A=[N][128] bf16 -> lo/hi halves out), fused att dots ----------
template<int F>
__global__ __launch_bounds__(256) void gemm_mfma_kernel(
    const unsigned short* __restrict__ AAll, const float* __restrict__ W,
    const float* __restrict__ atts, const float* __restrict__ attd,
    unsigned short* __restrict__ OloAll, unsigned short* __restrict__ OhiAll,
    float* __restrict__ aSAll, float* __restrict__ aDAll)
{
  int b = blockIdx.y;
  const unsigned short* A = AAll + (size_t)b*N_NODES*128;
  unsigned short* Olo = OloAll + (size_t)b*N_NODES*64;
  unsigned short* Ohi = (F == 128) ? (OhiAll + (size_t)b*N_NODES*64) : nullptr;
  float* a_s = aSAll + b*N_NODES;
  float* a_d = aDAll + b*N_NODES;
  constexpr int NT = F/16;
  constexpr int KP = 136;
  __shared__ unsigned short Wb[F*KP];
  int tid = threadIdx.x;
  for (int idx = tid; idx < 128*F; idx += 256){
    int k = idx / F, col = idx % F;
    Wb[col*KP + k] = f2bf(W[idx]);
  }
  __syncthreads();
  int wave = tid >> 6, lane = tid & 63;
  int r0w = blockIdx.x*64 + wave*16;
  int arow = r0w + (lane & 15);
  bool av = arow < N_NODES;
  f32x4 acc[NT];
  #pragma unroll
  for (int nt = 0; nt < NT; ++nt) acc[nt] = 0.f;
  #pragma unroll
  for (int step = 0; step < 4; ++step){
    int kbase = step*32 + (lane>>4)*8;
    uint4 araw = av ? *reinterpret_cast<const uint4*>(&A[(size_t)arow*128 + kbase])
                    : make_uint4(0,0,0,0);
    bf16v af = __builtin_bit_cast(bf16v, araw);
    #pragma unroll
    for (int nt = 0; nt < NT; ++nt){
      uint4 braw = *reinterpret_cast<const uint4*>(&Wb[(nt*16 + (lane&15))*KP + kbase]);
      bf16v bfr = __builtin_bit_cast(bf16v, braw);
      acc[nt] = __builtin_amdgcn_mfma_f32_16x16x32_bf16(af, bfr, acc[nt], 0, 0, 0);
    }
  }
  float ps[4] = {0,0,0,0}, pd[4] = {0,0,0,0};
  #pragma unroll
  for (int nt = 0; nt < NT; ++nt){
    int col = nt*16 + (lane&15);
    float vs = atts[col], vd = attd[col];
    unsigned short* O = (F == 64 || nt < 4) ? Olo : Ohi;
    int co = (F == 64 || nt < 4) ? col : col - 64;
    #pragma unroll
    for (int reg = 0; reg < 4; ++reg){
      int row = r0w + (lane>>4)*4 + reg;
      float v = acc[nt][reg];
      if (row < N_NODES) O[(size_t)row*64 + co] = f2bf(v);
      ps[reg] += v*vs;
      pd[reg] += v*vd;
    }
  }
  #pragma unroll
  for (int reg = 0; reg < 4; ++reg){
    float s = ps[reg], d = pd[reg];
    #pragma unroll
    for (int o = 1; o < 16; o <<= 1){ s += __shfl_xor(s, o); d += __shfl_xor(d, o); }
    int row = r0w + (lane>>4)*4 + reg;
    if ((lane & 15) == 0 && row < N_NODES){ a_s[row] = s*LOG2E; a_d[row] = d*LOG2E; }
  }
}

// ---------- aggregation v8: 64-feat half tables (L2-resident), 2 dsts/wave, exp2 ----------
// SPLIT: grid 4*(N/8); class = bid&3 -> (branch, half); each XCD serves one class.
// !SPLIT (layer 3): grid 2*(N/8); class = bid&1.
template<int OUTS, bool SPLIT>
__global__ __launch_bounds__(256) void aggregate_kernel(
    const unsigned short* __restrict__ tabLoAll, const unsigned short* __restrict__ tabHiAll,
    const float* __restrict__ aSAll, const float* __restrict__ aDAll,
    const unsigned* __restrict__ edgAll, const int2* __restrict__ rowp2All,
    const float* __restrict__ scal, int l,
    const float* __restrict__ bias,
    unsigned short* __restrict__ outbAll)
{
  int bid = blockIdx.x;
  int b = bid & 1;
  int hf = SPLIT ? ((bid >> 1) & 1) : 0;
  int grpidx = SPLIT ? (bid >> 2) : (bid >> 1);
  const unsigned short* tab = ((SPLIT && hf) ? tabHiAll : tabLoAll) + (size_t)b*N_NODES*64;
  const float* a_s = aSAll + b*N_NODES;
  const float* a_d = aDAll + b*N_NODES;
  const unsigned* edges = edgAll + (size_t)b*STAGEN;
  const int2* rowp2 = rowp2All + (size_t)b*N_NODES;
  __shared__ uint2 sp[4][64];
  int wv = threadIdx.x >> 6;
  int lane = threadIdx.x & 63;
  int half = lane >> 5;
  int hl = lane & 31;
  int d = grpidx*8 + wv*2 + half;
  int sub = hl & 15, grp = hl >> 4;
  const char* hb2 = (const char*)tab + sub*8;    // 8B slice of 128B row
  float c = scal[2+l]*LOG2E;
  float ae_self = (scal[b] * (1.0f/N_EDGES)) * c;
  float add_ = a_d[d];
  float p_self = exp2f(fminf(leaky02(a_s[d] + add_ + ae_self), 86.f));
  float dsum = 0.f;
  f32x2 acc[2];
  acc[0] = (f32x2){0.f, 0.f};
  acc[1] = (f32x2){0.f, 0.f};
  if (grp == 0){
    f32x2 pself2 = {p_self, p_self};
    uint2 q = *reinterpret_cast<const uint2*>(hb2 + ((unsigned)d << 7));
    pkfma(acc[0], (f32x2){bflo(q.x), bfhi(q.x)}, pself2);
    pkfma(acc[1], (f32x2){bflo(q.y), bfhi(q.y)}, pself2);
  }
  int2 r2 = rowp2[d];
  int e0 = r2.x, deg = r2.y - r2.x;
  int degmax = max(deg, __shfl_xor(deg, 32));
  const int cap = (int)STAGEN - 1;
  unsigned eRec = edges[min(e0 + hl, cap)];
  for (int ch = 0; ch < degmax; ch += 32){
    int n = deg - ch;
    unsigned eNext = edges[min(e0 + ch + 32 + hl, cap)];
    unsigned s0 = eRec & 0xFFFFu;
    float aval = a_s[s0];
    unsigned off0 = 0;
    float p0 = 0.f;
    if (hl < n){
      p0 = exp2f(fminf(leaky02(aval + add_ + c*bfhi(eRec)), 86.f));
      off0 = s0 << 7;
    }
    dsum += p0;
    sp[wv][lane] = make_uint2(off0, __float_as_uint(p0));
    int nmax = min(32, degmax - ch);
    #pragma unroll 4
    for (int e8 = 0; e8 < nmax; e8 += 8){
      int base = half*32 + e8 + grp;
      uint2 r0 = sp[wv][base];
      uint2 r1 = sp[wv][base + 2];
      uint2 rr2 = sp[wv][base + 4];
      uint2 r3 = sp[wv][base + 6];
      f32x2 a0 = {__uint_as_float(r0.y), __uint_as_float(r0.y)};
      f32x2 a1 = {__uint_as_float(r1.y), __uint_as_float(r1.y)};
      f32x2 a2 = {__uint_as_float(rr2.y), __uint_as_float(rr2.y)};
      f32x2 a3 = {__uint_as_float(r3.y), __uint_as_float(r3.y)};
      uint2 q0 = *reinterpret_cast<const uint2*>(hb2 + r0.x);
      uint2 q1 = *reinterpret_cast<const uint2*>(hb2 + r1.x);
      uint2 q2 = *reinterpret_cast<const uint2*>(hb2 + rr2.x);
      uint2 q3 = *reinterpret_cast<const uint2*>(hb2 + r3.x);
      pkfma(acc[0], (f32x2){bflo(q0.x), bfhi(q0.x)}, a0);
      pkfma(acc[1], (f32x2){bflo(q0.y), bfhi(q0.y)}, a0);
      pkfma(acc[0], (f32x2){bflo(q1.x), bfhi(q1.x)}, a1);
      pkfma(acc[1], (f32x2){bflo(q1.y), bfhi(q1.y)}, a1);
      pkfma(acc[0], (f32x2){bflo(q2.x), bfhi(q2.x)}, a2);
      pkfma(acc[1], (f32x2){bflo(q2.y), bfhi(q2.y)}, a2);
      pkfma(acc[0], (f32x2){bflo(q3.x), bfhi(q3.x)}, a3);
      pkfma(acc[1], (f32x2){bflo(q3.y), bfhi(q3.y)}, a3);
    }
    eRec = eNext;
  }
  #pragma unroll
  for (int o = 16; o; o >>= 1) dsum += __shfl_xor(dsum, o);
  float denom = p_self + dsum;
  float inv = 1.0f/denom;
  float vv[4];
  #pragma unroll
  for (int i = 0; i < 2; ++i){
    float v0 = acc[i].x, v1 = acc[i].y;
    v0 += __shfl_xor(v0, 16);
    v1 += __shfl_xor(v1, 16);
    vv[2*i]   = eluf(v0*inv + bias[hf*64 + 4*sub + 2*i]);
    vv[2*i+1] = eluf(v1*inv + bias[hf*64 + 4*sub + 2*i+1]);
  }
  if (grp == 0){
    unsigned short* outb = outbAll + (size_t)b*N_NODES*OUTS;
    uint2 o;
    o.x = (unsigned int)f2bf(vv[0]) | ((unsigned int)f2bf(vv[1]) << 16);
    o.y = (unsigned int)f2bf(vv[2]) | ((unsigned int)f2bf(vv[3]) << 16);
    *reinterpret_cast<uint2*>(&outb[(size_t)d*OUTS + hf*64 + 4*sub]) = o;
  }
}

// ---------- fused mean-pool (bf16 in) + final linear ----------
__global__ __launch_bounds__(256) void pool_final_kernel(
    const unsigned short* __restrict__ buf, const int* __restrict__ gb,
    const float* __restrict__ xn0, const float* __restrict__ xn1,
    const float* __restrict__ linW, const float* __restrict__ linb,
    float* __restrict__ out)
{
  int bg = blockIdx.x;
  int b = bg >> 8, g = bg & 255;
  __shared__ float Wl[80*64];
  __shared__ float red[4][64];
  __shared__ float mf[64];
  int tid = threadIdx.x;
  for (int i = tid; i < 80*64; i += 256) Wl[i] = linW[i];
  const unsigned short* x = buf + (size_t)b*N_NODES*64;
  const int* gbb = gb + b*257;
  int s = gbb[g], e = gbb[g+1];
  int f = tid & 63, rg = tid >> 6;
  float acc = 0.f;
  for (int r = s + rg; r < e; r += 4) acc += bfs(x[(size_t)r*64 + f]);
  red[rg][f] = acc;
  __syncthreads();
  if (rg == 0)
    mf[f] = (red[0][f]+red[1][f]+red[2][f]+red[3][f]) / fmaxf((float)(e - s), 1.0f);
  __syncthreads();
  if (tid < 64){
    int j = tid;
    const float* xn = b ? xn1 : xn0;
    float a2 = linb[j];
    #pragma unroll 8
    for (int k = 0; k < 64; ++k) a2 += mf[k] * Wl[k*64 + j];
    #pragma unroll
    for (int k = 0; k < 16; ++k) a2 += xn[g*16+k] * Wl[(64+k)*64 + j];
    out[(size_t)(b*N_GRAPHS + g)*64 + j] = a2;
  }
}

extern "C" void kernel_launch(void* const* d_in, const int* in_sizes, int n_in,
                              void* d_out, int out_size, void* d_ws, size_t ws_size,
                              hipStream_t stream)
{
  const float* x1   = (const float*)d_in[0];
  const float* x2   = (const float*)d_in[1];
  const int*   ei1  = (const int*)d_in[2];
  const int*   ei2  = (const int*)d_in[3];
  const int*   bat1 = (const int*)d_in[4];
  const int*   bat2 = (const int*)d_in[5];
  const float* xn1  = (const float*)d_in[6];
  const float* xn2  = (const float*)d_in[7];
  const float* ec1  = (const float*)d_in[8];
  const float* ec2  = (const float*)d_in[9];
  const float* W[3]   = {(const float*)d_in[10], (const float*)d_in[16], (const float*)d_in[22]};
  const float* as_[3] = {(const float*)d_in[11], (const float*)d_in[17], (const float*)d_in[23]};
  const float* ad_[3] = {(const float*)d_in[12], (const float*)d_in[18], (const float*)d_in[24]};
  const float* We[3]  = {(const float*)d_in[13], (const float*)d_in[19], (const float*)d_in[25]};
  const float* ae[3]  = {(const float*)d_in[14], (const float*)d_in[20], (const float*)d_in[26]};
  const float* bb[3]  = {(const float*)d_in[15], (const float*)d_in[21], (const float*)d_in[27]};
  const float* linW = (const float*)d_in[28];
  const float* linb = (const float*)d_in[29];
  float* out = (float*)d_out;

  char* ws = (char*)d_ws;
  size_t off = 0;
  auto alloc = [&](size_t bytes)->char*{
    char* p = ws + off;
    off = (off + bytes + 255) & ~(size_t)255;
    return p;
  };
  unsigned short* tabLo = (unsigned short*)alloc((size_t)2*N_NODES*64*2); // gather halves
  unsigned short* tabHi = (unsigned short*)alloc((size_t)2*N_NODES*64*2);
  unsigned short* hbU   = (unsigned short*)alloc((size_t)2*N_NODES*128*2); // agg out / GEMM A
  float* aS   = (float*)alloc((size_t)2*N_NODES*4);
  float* aD   = (float*)alloc((size_t)2*N_NODES*4);
  int* bcur   = (int*)alloc((size_t)2*NBUCK*CURP*4);
  int2* rowp2 = (int2*)alloc((size_t)2*N_NODES*8);
  uint2* stage = (uint2*)alloc((size_t)2*STAGEN*8);
  unsigned* final_ = (unsigned*)alloc((size_t)2*STAGEN*4);
  float* part = (float*)alloc((size_t)2*NC*4);
  int* gb     = (int*)alloc((size_t)2*257*4);
  float* scal = (float*)alloc(64);

  setup_kernel<<<2, 512, 0, stream>>>(bat1, bat2,
      We[0], ae[0], We[1], ae[1], We[2], ae[2], bcur, gb, scal);
  binC_kernel<<<dim3(NC,2), 256, 0, stream>>>(ei1, ei2, ec1, ec2, bcur, stage, part);
  binD_kernel<<<dim3(NBUCK,2), 256, 0, stream>>>(stage, bcur, part, final_, rowp2, scal);

  const int AGG4 = 4*(N_NODES/8);  // 10000 blocks (branch x half classes)
  const int AGG2 = 2*(N_NODES/8);  // 5000 blocks

  // layer 1: K=7 -> F=128 (lo/hi halves)
  node_linear1_kernel<7,128><<<dim3(1024,2), 256, 0, stream>>>(
      x1, x2, W[0], as_[0], ad_[0], tabLo, tabHi, aS, aD);
  aggregate_kernel<128,true><<<AGG4, 256, 0, stream>>>(
      tabLo, tabHi, aS, aD, final_, rowp2, scal, 0, bb[0], hbU);

  // layer 2: MFMA 128->128 (A unified, out lo/hi)
  gemm_mfma_kernel<128><<<dim3((N_NODES+63)/64,2), 256, 0, stream>>>(
      hbU, W[1], as_[1], ad_[1], tabLo, tabHi, aS, aD);
  aggregate_kernel<128,true><<<AGG4, 256, 0, stream>>>(
      tabLo, tabHi, aS, aD, final_, rowp2, scal, 1, bb[1], hbU);

  // layer 3: MFMA 128->64 (out single table tabLo)
  gemm_mfma_kernel<64><<<dim3((N_NODES+63)/64,2), 256, 0, stream>>>(
      hbU, W[2], as_[2], ad_[2], tabLo, nullptr, aS, aD);
  aggregate_kernel<64,false><<<AGG2, 256, 0, stream>>>(
      tabLo, nullptr, aS, aD, final_, rowp2, scal, 2, bb[2], tabHi);

  pool_final_kernel<<<2*N_GRAPHS, 256, 0, stream>>>(
      tabHi, gb, xn1, xn2, linW, linb, out);
}

// Round 20
// 180.947 us; speedup vs baseline: 1.1135x; 1.1135x over previous
//
#include <hip/hip_runtime.h>
#include <hip/hip_bf16.h>
#include <hip/hip_fp16.h>

#define N_NODES 20000
#define N_EDGES 640000
#define N_GRAPHS 256
#define NBUCK 313                    // ceil(20000/64) buckets of 64 dsts
#define NC 160                       // binC blocks per branch
#define EPC 4000                     // edges per binC block (160*4000 = 640000)
#define DCAP 2560                    // per-bucket region capacity (mean 2045 + 11 sigma)
#define CURP 16                      // bcur padding: 16 ints = 64B per bucket
#define STAGEN ((size_t)NBUCK*DCAP)  // 801,280 records per branch
#define LOG2E 1.44269504f

typedef short bf16v __attribute__((ext_vector_type(8)));   // 8 bf16 (4 VGPRs)
typedef float f32x4 __attribute__((ext_vector_type(4)));
typedef float f32x2 __attribute__((ext_vector_type(2)));

__device__ __forceinline__ float leaky02(float x){ return x > 0.f ? x : 0.2f*x; }
__device__ __forceinline__ float eluf(float x){ return x > 0.f ? x : (__expf(x) - 1.f); }
__device__ __forceinline__ unsigned short f2bf(float x){
  __hip_bfloat16 t = __float2bfloat16(x);
  return *reinterpret_cast<unsigned short*>(&t);
}
__device__ __forceinline__ float bflo(unsigned int u){ return __uint_as_float(u << 16); }
__device__ __forceinline__ float bfhi(unsigned int u){ return __uint_as_float(u & 0xffff0000u); }
__device__ __forceinline__ float bfs(unsigned short u){ return __uint_as_float(((unsigned)u) << 16); }
__device__ __forceinline__ void pkfma(f32x2& acc, f32x2 a, f32x2 b){
  asm volatile("v_pk_fma_f32 %0, %1, %2, %0" : "+v"(acc) : "v"(a), "v"(b));
}

// ---------- setup: bucket cursors + graph bounds + prep_c ----------
__global__ __launch_bounds__(512) void setup_kernel(
    const int* __restrict__ bat0, const int* __restrict__ bat1,
    const float* __restrict__ We1, const float* __restrict__ ae1,
    const float* __restrict__ We2, const float* __restrict__ ae2,
    const float* __restrict__ We3, const float* __restrict__ ae3,
    int* __restrict__ bcur, int* __restrict__ gb, float* __restrict__ scal)
{
  int b = blockIdx.x;
  int tid = threadIdx.x;
  if (tid < NBUCK) bcur[((size_t)b*NBUCK + tid)*CURP] = tid*DCAP;
  {
    const int* batch = b ? bat1 : bat0;
    int* gbb = gb + b*257;
    if (tid <= N_GRAPHS){
      int g = tid, lo = 0, hi = N_NODES;
      while (lo < hi){ int mid = (lo+hi) >> 1; if (batch[mid] < g) lo = mid+1; else hi = mid; }
      gbb[g] = lo;
    }
  }
  if (b == 0){
    int wv = tid >> 6, lane = tid & 63;
    if (wv < 3){
      const float* We = wv==0 ? We1 : (wv==1 ? We2 : We3);
      const float* ae = wv==0 ? ae1 : (wv==1 ? ae2 : ae3);
      int F = (wv==2) ? 64 : 128;
      float s = 0.f;
      for (int i = lane; i < F; i += 64) s += We[i]*ae[i];
      for (int o = 32; o; o >>= 1) s += __shfl_down(s, o);
      if (lane == 0) scal[2+wv] = s;
    }
  }
}

// ---------- binC: histogram-then-place LDS binning into padded regions + ec partials ----------
__global__ __launch_bounds__(256) void binC_kernel(
    const int* __restrict__ ei0, const int* __restrict__ ei1,
    const float* __restrict__ ec0, const float* __restrict__ ec1,
    int* __restrict__ bcur, uint2* __restrict__ stage, float* __restrict__ part)
{
  int b = blockIdx.y;
  const int* srcp = (b ? ei1 : ei0);
  const int* dstp = srcp + N_EDGES;
  const float* ec = b ? ec1 : ec0;
  int* bcurb = bcur + (size_t)b*NBUCK*CURP;
  uint2* stageb = stage + (size_t)b*STAGEN;
  __shared__ uint2 recs[EPC];
  __shared__ int hist[NBUCK], rbase[NBUCK], rcur[NBUCK];
  int tid = threadIdx.x;
  for (int j = tid; j < NBUCK; j += 256){ hist[j] = 0; rcur[j] = 0; }
  __syncthreads();
  int e0 = blockIdx.x*EPC;
  float v = 0.f;
  for (int r = tid; r < EPC; r += 256){
    int i = e0 + r;
    int d = dstp[i];
    int bk = d >> 6;
    uint2 rec;
    rec.x = (unsigned)srcp[i] | ((unsigned)(d & 63) << 16);
    float e = ec[i];
    v += e;
    rec.y = ((unsigned)f2bf(e) << 16) | (unsigned)bk;
    recs[r] = rec;
    atomicAdd(&hist[bk], 1);
  }
  __syncthreads();
  for (int j = tid; j < NBUCK; j += 256){
    int h = hist[j];
    rbase[j] = h ? atomicAdd(&bcurb[j*CURP], h) : 0;
  }
  __syncthreads();
  for (int r = tid; r < EPC; r += 256){
    uint2 rc = recs[r];
    int bk = (int)(rc.y & 0xFFFFu);
    int p = rbase[bk] + atomicAdd(&rcur[bk], 1);
    if (p < (bk + 1)*DCAP) stageb[p] = rc;   // overflow clamp (11-sigma margin)
  }
  // ec partial sum
  for (int o = 32; o; o >>= 1) v += __shfl_down(v, o);
  __shared__ float wr[4];
  int lane = tid & 63, wv = tid >> 6;
  if (lane == 0) wr[wv] = v;
  __syncthreads();
  if (tid == 0) part[b*NC + blockIdx.x] = wr[0]+wr[1]+wr[2]+wr[3];
}

// ---------- binD: per-bucket counting sort -> padded CSR + int2 rowp2 (+ ec total in g==0) ----------
__global__ __launch_bounds__(256) void binD_kernel(
    const uint2* __restrict__ stage, const int* __restrict__ bcur,
    const float* __restrict__ part,
    unsigned* __restrict__ final_, int2* __restrict__ rowp2, float* __restrict__ scal)
{
  int b = blockIdx.y;
  int g = blockIdx.x;
  int tid = threadIdx.x;
  if (g == 0){   // ec total for this branch
    float s = 0.f;
    for (int i = tid; i < NC; i += 256) s += part[b*NC + i];
    for (int o = 32; o; o >>= 1) s += __shfl_down(s, o);
    __shared__ float fr[4];
    if ((tid & 63) == 0) fr[tid >> 6] = s;
    __syncthreads();
    if (tid == 0) scal[b] = fr[0]+fr[1]+fr[2]+fr[3];
  }
  const uint2* stageb = stage + (size_t)b*STAGEN;
  unsigned* finb = final_ + (size_t)b*STAGEN;
  int2* rowb = rowp2 + (size_t)b*N_NODES;
  int cb = g*DCAP;
  int n = min(bcur[((size_t)b*NBUCK + g)*CURP] - cb, DCAP);
  __shared__ uint2 recs[DCAP];
  __shared__ int cnt64[64], cur64[64], off64[64];
  if (tid < 64) cnt64[tid] = 0;
  __syncthreads();
  for (int r = tid; r < n; r += 256){
    uint2 rc = stageb[cb + r];
    recs[r] = rc;
    atomicAdd(&cnt64[(rc.x >> 16) & 63], 1);
  }
  __syncthreads();
  if (tid == 0){
    int acc = 0;
    for (int dl = 0; dl < 64; ++dl){
      off64[dl] = acc; cur64[dl] = acc; acc += cnt64[dl];
    }
  }
  __syncthreads();
  int nd = min(64, N_NODES - g*64);
  if (tid < nd)
    rowb[g*64 + tid] = make_int2(cb + off64[tid], cb + off64[tid] + cnt64[tid]);
  for (int r = tid; r < n; r += 256){
    uint2 rc = recs[r];
    int dl = (rc.x >> 16) & 63;
    int p = atomicAdd(&cur64[dl], 1);
    finb[cb + p] = (rc.y & 0xFFFF0000u) | (rc.x & 0xFFFFu);
  }
}

// ---------- layer 1: K=7 scalar GEMM + att dots (prescaled), bf16 out ----------
template<int K, int F>
__global__ __launch_bounds__(256) void node_linear1_kernel(
    const float* __restrict__ x0, const float* __restrict__ x1,
    const float* __restrict__ W,
    const float* __restrict__ atts, const float* __restrict__ attd,
    unsigned short* __restrict__ hbAll, float* __restrict__ aSAll, float* __restrict__ aDAll)
{
  int b = blockIdx.y;
  const float* x = b ? x1 : x0;
  unsigned short* hb = hbAll + (size_t)b*N_NODES*128;
  float* a_s = aSAll + b*N_NODES;
  float* a_d = aDAll + b*N_NODES;
  constexpr int ROWS = 256 / F; // 2
  __shared__ float Wl[K*F];
  __shared__ float xl[ROWS*K];
  __shared__ float swv[4], dwv[4];
  int tid = threadIdx.x;
  for (int i = tid; i < K*F; i += 256) Wl[i] = W[i];
  int f = tid % F;
  int lr = tid / F;
  float vs = atts[f], vd = attd[f];
  const int ntiles = (N_NODES + ROWS - 1)/ROWS;
  for (int t = blockIdx.x; t < ntiles; t += gridDim.x){
    int r0 = t*ROWS;
    __syncthreads();
    for (int i = tid; i < ROWS*K; i += 256){
      int r = i / K, k = i % K;
      int row = r0 + r;
      xl[i] = (row < N_NODES) ? x[row*K + k] : 0.f;
    }
    __syncthreads();
    float acc = 0.f;
    #pragma unroll
    for (int k = 0; k < K; ++k) acc += xl[lr*K + k] * Wl[k*F + f];
    int row = r0 + lr;
    if (row < N_NODES) hb[row*F + f] = f2bf(acc);
    float s = acc*vs, d = acc*vd;
    #pragma unroll
    for (int o = 32; o; o >>= 1){ s += __shfl_down(s, o); d += __shfl_down(d, o); }
    int wv = tid >> 6;
    if ((tid & 63) == 0){ swv[wv] = s; dwv[wv] = d; }
    __syncthreads();
    if (f == 0 && row < N_NODES){
      a_s[row] = (swv[2*lr] + swv[2*lr+1])*LOG2E;
      a_d[row] = (dwv[2*lr] + dwv[2*lr+1])*LOG2E;
    }
  }
}

// ---------- layers 2/3: MFMA GEMM (A bf16 -> bf16 out), fused att dots (prescaled) ----------
template<int F>
__global__ __launch_bounds__(256) void gemm_mfma_kernel(
    const unsigned short* __restrict__ AAll, const float* __restrict__ W,
    const float* __restrict__ atts, const float* __restrict__ attd,
    unsigned short* __restrict__ hbAll, float* __restrict__ aSAll, float* __restrict__ aDAll)
{
  int b = blockIdx.y;
  const unsigned short* A = AAll + (size_t)b*N_NODES*128;
  unsigned short* hb = hbAll + (size_t)b*N_NODES*128;   // branch offset ALWAYS 128 (row stride F)
  float* a_s = aSAll + b*N_NODES;
  float* a_d = aDAll + b*N_NODES;
  constexpr int NT = F/16;
  constexpr int KP = 136;
  __shared__ unsigned short Wb[F*KP];
  int tid = threadIdx.x;
  for (int idx = tid; idx < 128*F; idx += 256){
    int k = idx / F, col = idx % F;
    Wb[col*KP + k] = f2bf(W[idx]);
  }
  __syncthreads();
  int wave = tid >> 6, lane = tid & 63;
  int r0w = blockIdx.x*64 + wave*16;
  int arow = r0w + (lane & 15);
  bool av = arow < N_NODES;
  f32x4 acc[NT];
  #pragma unroll
  for (int nt = 0; nt < NT; ++nt) acc[nt] = 0.f;
  #pragma unroll
  for (int step = 0; step < 4; ++step){
    int kbase = step*32 + (lane>>4)*8;
    uint4 araw = av ? *reinterpret_cast<const uint4*>(&A[(size_t)arow*128 + kbase])
                    : make_uint4(0,0,0,0);
    bf16v af = __builtin_bit_cast(bf16v, araw);
    #pragma unroll
    for (int nt = 0; nt < NT; ++nt){
      uint4 braw = *reinterpret_cast<const uint4*>(&Wb[(nt*16 + (lane&15))*KP + kbase]);
      bf16v bfr = __builtin_bit_cast(bf16v, braw);
      acc[nt] = __builtin_amdgcn_mfma_f32_16x16x32_bf16(af, bfr, acc[nt], 0, 0, 0);
    }
  }
  float ps[4] = {0,0,0,0}, pd[4] = {0,0,0,0};
  #pragma unroll
  for (int nt = 0; nt < NT; ++nt){
    int col = nt*16 + (lane&15);
    float vs = atts[col], vd = attd[col];
    #pragma unroll
    for (int reg = 0; reg < 4; ++reg){
      int row = r0w + (lane>>4)*4 + reg;
      float v = acc[nt][reg];
      if (row < N_NODES) hb[(size_t)row*F + col] = f2bf(v);
      ps[reg] += v*vs;
      pd[reg] += v*vd;
    }
  }
  #pragma unroll
  for (int reg = 0; reg < 4; ++reg){
    float s = ps[reg], d = pd[reg];
    #pragma unroll
    for (int o = 1; o < 16; o <<= 1){ s += __shfl_xor(s, o); d += __shfl_xor(d, o); }
    int row = r0w + (lane>>4)*4 + reg;
    if ((lane & 15) == 0 && row < N_NODES){ a_s[row] = s*LOG2E; a_d[row] = d*LOG2E; }
  }
}

// ---------- aggregation v7b: 2 dsts/wave, edge prefetch, exp2, bf16 out ----------
// grid: 1-D, 2*(N_NODES/8) blocks; branch = bid&1.
template<int F>
__global__ __launch_bounds__(256) void aggregate_kernel(
    const unsigned short* __restrict__ hbAll,
    const float* __restrict__ aSAll, const float* __restrict__ aDAll,
    const unsigned* __restrict__ edgAll, const int2* __restrict__ rowp2All,
    const float* __restrict__ scal, int l,
    const float* __restrict__ bias,
    unsigned short* __restrict__ outbAll)
{
  constexpr int PERL = F/16;   // 8 (F=128) or 4 (F=64)
  constexpr int PERH = PERL/2;
  constexpr int RSH = (F == 128) ? 8 : 7;
  constexpr int SUBB = (F == 128) ? 16 : 8;
  int bid = blockIdx.x;
  int b = bid & 1;
  const unsigned short* hb = hbAll + (size_t)b*N_NODES*128;
  const float* a_s = aSAll + b*N_NODES;
  const float* a_d = aDAll + b*N_NODES;
  const unsigned* edges = edgAll + (size_t)b*STAGEN;
  const int2* rowp2 = rowp2All + (size_t)b*N_NODES;
  __shared__ uint2 sp[4][64];
  int wv = threadIdx.x >> 6;
  int lane = threadIdx.x & 63;
  int half = lane >> 5;        // 0 = dstA, 1 = dstB
  int hl = lane & 31;
  int d = (bid >> 1)*8 + wv*2 + half;   // 20000 % 8 == 0
  int sub = hl & 15, grp = hl >> 4;
  const char* hb2 = (const char*)hb + sub*SUBB;
  float c = scal[2+l]*LOG2E;
  float ae_self = (scal[b] * (1.0f/N_EDGES)) * c;
  float add_ = a_d[d];
  float p_self = exp2f(fminf(leaky02(a_s[d] + add_ + ae_self), 86.f));
  float dsum = 0.f;
  f32x2 acc[PERH];
  #pragma unroll
  for (int i = 0; i < PERH; ++i) acc[i] = (f32x2){0.f, 0.f};
  if (grp == 0){
    f32x2 pself2 = {p_self, p_self};
    if (PERL == 8){
      uint4 q = *reinterpret_cast<const uint4*>(hb2 + ((unsigned)d << RSH));
      pkfma(acc[0], (f32x2){bflo(q.x), bfhi(q.x)}, pself2);
      pkfma(acc[1], (f32x2){bflo(q.y), bfhi(q.y)}, pself2);
      pkfma(acc[2], (f32x2){bflo(q.z), bfhi(q.z)}, pself2);
      pkfma(acc[3], (f32x2){bflo(q.w), bfhi(q.w)}, pself2);
    } else {
      uint2 q = *reinterpret_cast<const uint2*>(hb2 + ((unsigned)d << RSH));
      pkfma(acc[0], (f32x2){bflo(q.x), bfhi(q.x)}, pself2);
      pkfma(acc[1], (f32x2){bflo(q.y), bfhi(q.y)}, pself2);
    }
  }
  int2 r2 = rowp2[d];
  int e0 = r2.x, deg = r2.y - r2.x;
  int degmax = max(deg, __shfl_xor(deg, 32));
  const int cap = (int)STAGEN - 1;
  unsigned eRec = edges[min(e0 + hl, cap)];          // prefetch chunk 0
  for (int ch = 0; ch < degmax; ch += 32){
    int n = deg - ch;
    unsigned eNext = edges[min(e0 + ch + 32 + hl, cap)];   // prefetch next chunk early
    unsigned s0 = eRec & 0xFFFFu;
    float aval = a_s[s0];
    unsigned off0 = 0;
    float p0 = 0.f;
    if (hl < n){
      p0 = exp2f(fminf(leaky02(aval + add_ + c*bfhi(eRec)), 86.f));
      off0 = s0 << RSH;
    }
    dsum += p0;
    sp[wv][lane] = make_uint2(off0, __float_as_uint(p0));
    int nmax = min(32, degmax - ch);
    #pragma unroll 4
    for (int e8 = 0; e8 < nmax; e8 += 8){
      int base = half*32 + e8 + grp;
      uint2 r0 = sp[wv][base];
      uint2 r1 = sp[wv][base + 2];
      uint2 rr2 = sp[wv][base + 4];
      uint2 r3 = sp[wv][base + 6];
      f32x2 a0 = {__uint_as_float(r0.y), __uint_as_float(r0.y)};
      f32x2 a1 = {__uint_as_float(r1.y), __uint_as_float(r1.y)};
      f32x2 a2 = {__uint_as_float(rr2.y), __uint_as_float(rr2.y)};
      f32x2 a3 = {__uint_as_float(r3.y), __uint_as_float(r3.y)};
      if (PERL == 8){
        uint4 q0 = *reinterpret_cast<const uint4*>(hb2 + r0.x);
        uint4 q1 = *reinterpret_cast<const uint4*>(hb2 + r1.x);
        uint4 q2 = *reinterpret_cast<const uint4*>(hb2 + rr2.x);
        uint4 q3 = *reinterpret_cast<const uint4*>(hb2 + r3.x);
        pkfma(acc[0], (f32x2){bflo(q0.x), bfhi(q0.x)}, a0);
        pkfma(acc[1], (f32x2){bflo(q0.y), bfhi(q0.y)}, a0);
        pkfma(acc[2], (f32x2){bflo(q0.z), bfhi(q0.z)}, a0);
        pkfma(acc[3], (f32x2){bflo(q0.w), bfhi(q0.w)}, a0);
        pkfma(acc[0], (f32x2){bflo(q1.x), bfhi(q1.x)}, a1);
        pkfma(acc[1], (f32x2){bflo(q1.y), bfhi(q1.y)}, a1);
        pkfma(acc[2], (f32x2){bflo(q1.z), bfhi(q1.z)}, a1);
        pkfma(acc[3], (f32x2){bflo(q1.w), bfhi(q1.w)}, a1);
        pkfma(acc[0], (f32x2){bflo(q2.x), bfhi(q2.x)}, a2);
        pkfma(acc[1], (f32x2){bflo(q2.y), bfhi(q2.y)}, a2);
        pkfma(acc[2], (f32x2){bflo(q2.z), bfhi(q2.z)}, a2);
        pkfma(acc[3], (f32x2){bflo(q2.w), bfhi(q2.w)}, a2);
        pkfma(acc[0], (f32x2){bflo(q3.x), bfhi(q3.x)}, a3);
        pkfma(acc[1], (f32x2){bflo(q3.y), bfhi(q3.y)}, a3);
        pkfma(acc[2], (f32x2){bflo(q3.z), bfhi(q3.z)}, a3);
        pkfma(acc[3], (f32x2){bflo(q3.w), bfhi(q3.w)}, a3);
      } else {
        uint2 q0 = *reinterpret_cast<const uint2*>(hb2 + r0.x);
        uint2 q1 = *reinterpret_cast<const uint2*>(hb2 + r1.x);
        uint2 q2 = *reinterpret_cast<const uint2*>(hb2 + rr2.x);
        uint2 q3 = *reinterpret_cast<const uint2*>(hb2 + r3.x);
        pkfma(acc[0], (f32x2){bflo(q0.x), bfhi(q0.x)}, a0);
        pkfma(acc[1], (f32x2){bflo(q0.y), bfhi(q0.y)}, a0);
        pkfma(acc[0], (f32x2){bflo(q1.x), bfhi(q1.x)}, a1);
        pkfma(acc[1], (f32x2){bflo(q1.y), bfhi(q1.y)}, a1);
        pkfma(acc[0], (f32x2){bflo(q2.x), bfhi(q2.x)}, a2);
        pkfma(acc[1], (f32x2){bflo(q2.y), bfhi(q2.y)}, a2);
        pkfma(acc[0], (f32x2){bflo(q3.x), bfhi(q3.x)}, a3);
        pkfma(acc[1], (f32x2){bflo(q3.y), bfhi(q3.y)}, a3);
      }
    }
    eRec = eNext;
  }
  // denom reduce within 32-lane half
  #pragma unroll
  for (int o = 16; o; o >>= 1) dsum += __shfl_xor(dsum, o);
  float denom = p_self + dsum;
  float inv = 1.0f/denom;
  float vv[PERL];
  #pragma unroll
  for (int i = 0; i < PERH; ++i){
    float v0 = acc[i].x, v1 = acc[i].y;
    v0 += __shfl_xor(v0, 16);
    v1 += __shfl_xor(v1, 16);
    vv[2*i]   = eluf(v0*inv + bias[PERL*sub + 2*i]);
    vv[2*i+1] = eluf(v1*inv + bias[PERL*sub + 2*i+1]);
  }
  if (grp == 0){
    unsigned short* outb = outbAll + (size_t)b*N_NODES*F;
    if (PERL == 8){
      uint4 o;
      o.x = (unsigned int)f2bf(vv[0]) | ((unsigned int)f2bf(vv[1]) << 16);
      o.y = (unsigned int)f2bf(vv[2]) | ((unsigned int)f2bf(vv[3]) << 16);
      o.z = (unsigned int)f2bf(vv[4]) | ((unsigned int)f2bf(vv[5]) << 16);
      o.w = (unsigned int)f2bf(vv[6]) | ((unsigned int)f2bf(vv[7]) << 16);
      *reinterpret_cast<uint4*>(&outb[(size_t)d*F + 8*sub]) = o;
    } else {
      uint2 o;
      o.x = (unsigned int)f2bf(vv[0]) | ((unsigned int)f2bf(vv[1]) << 16);
      o.y = (unsigned int)f2bf(vv[2]) | ((unsigned int)f2bf(vv[3]) << 16);
      *reinterpret_cast<uint2*>(&outb[(size_t)d*F + 4*sub]) = o;
    }
  }
}

// ---------- fused mean-pool (bf16 in) + final linear ----------
__global__ __launch_bounds__(256) void pool_final_kernel(
    const unsigned short* __restrict__ buf, const int* __restrict__ gb,
    const float* __restrict__ xn0, const float* __restrict__ xn1,
    const float* __restrict__ linW, const float* __restrict__ linb,
    float* __restrict__ out)
{
  int bg = blockIdx.x;
  int b = bg >> 8, g = bg & 255;
  __shared__ float Wl[80*64];
  __shared__ float red[4][64];
  __shared__ float mf[64];
  int tid = threadIdx.x;
  for (int i = tid; i < 80*64; i += 256) Wl[i] = linW[i];
  const unsigned short* x = buf + (size_t)b*N_NODES*64;
  const int* gbb = gb + b*257;
  int s = gbb[g], e = gbb[g+1];
  int f = tid & 63, rg = tid >> 6;
  float acc = 0.f;
  for (int r = s + rg; r < e; r += 4) acc += bfs(x[(size_t)r*64 + f]);
  red[rg][f] = acc;
  __syncthreads();
  if (rg == 0)
    mf[f] = (red[0][f]+red[1][f]+red[2][f]+red[3][f]) / fmaxf((float)(e - s), 1.0f);
  __syncthreads();
  if (tid < 64){
    int j = tid;
    const float* xn = b ? xn1 : xn0;
    float a2 = linb[j];
    #pragma unroll 8
    for (int k = 0; k < 64; ++k) a2 += mf[k] * Wl[k*64 + j];
    #pragma unroll
    for (int k = 0; k < 16; ++k) a2 += xn[g*16+k] * Wl[(64+k)*64 + j];
    out[(size_t)(b*N_GRAPHS + g)*64 + j] = a2;
  }
}

extern "C" void kernel_launch(void* const* d_in, const int* in_sizes, int n_in,
                              void* d_out, int out_size, void* d_ws, size_t ws_size,
                              hipStream_t stream)
{
  const float* x1   = (const float*)d_in[0];
  const float* x2   = (const float*)d_in[1];
  const int*   ei1  = (const int*)d_in[2];
  const int*   ei2  = (const int*)d_in[3];
  const int*   bat1 = (const int*)d_in[4];
  const int*   bat2 = (const int*)d_in[5];
  const float* xn1  = (const float*)d_in[6];
  const float* xn2  = (const float*)d_in[7];
  const float* ec1  = (const float*)d_in[8];
  const float* ec2  = (const float*)d_in[9];
  const float* W[3]   = {(const float*)d_in[10], (const float*)d_in[16], (const float*)d_in[22]};
  const float* as_[3] = {(const float*)d_in[11], (const float*)d_in[17], (const float*)d_in[23]};
  const float* ad_[3] = {(const float*)d_in[12], (const float*)d_in[18], (const float*)d_in[24]};
  const float* We[3]  = {(const float*)d_in[13], (const float*)d_in[19], (const float*)d_in[25]};
  const float* ae[3]  = {(const float*)d_in[14], (const float*)d_in[20], (const float*)d_in[26]};
  const float* bb[3]  = {(const float*)d_in[15], (const float*)d_in[21], (const float*)d_in[27]};
  const float* linW = (const float*)d_in[28];
  const float* linb = (const float*)d_in[29];
  float* out = (float*)d_out;

  char* ws = (char*)d_ws;
  size_t off = 0;
  auto alloc = [&](size_t bytes)->char*{
    char* p = ws + off;
    off = (off + bytes + 255) & ~(size_t)255;
    return p;
  };
  unsigned short* hbA = (unsigned short*)alloc((size_t)2*N_NODES*128*2);
  unsigned short* hbB = (unsigned short*)alloc((size_t)2*N_NODES*128*2);
  float* aS   = (float*)alloc((size_t)2*N_NODES*4);
  float* aD   = (float*)alloc((size_t)2*N_NODES*4);
  int* bcur   = (int*)alloc((size_t)2*NBUCK*CURP*4);
  int2* rowp2 = (int2*)alloc((size_t)2*N_NODES*8);
  uint2* stage = (uint2*)alloc((size_t)2*STAGEN*8);
  unsigned* final_ = (unsigned*)alloc((size_t)2*STAGEN*4);
  float* part = (float*)alloc((size_t)2*NC*4);
  int* gb     = (int*)alloc((size_t)2*257*4);
  float* scal = (float*)alloc(64);

  setup_kernel<<<2, 512, 0, stream>>>(bat1, bat2,
      We[0], ae[0], We[1], ae[1], We[2], ae[2], bcur, gb, scal);
  binC_kernel<<<dim3(NC,2), 256, 0, stream>>>(ei1, ei2, ec1, ec2, bcur, stage, part);
  binD_kernel<<<dim3(NBUCK,2), 256, 0, stream>>>(stage, bcur, part, final_, rowp2, scal);

  const int AGG = 2*(N_NODES/8);  // 5000 blocks, branch = bid&1

  // layer 1: K=7 -> F=128
  node_linear1_kernel<7,128><<<dim3(1024,2), 256, 0, stream>>>(
      x1, x2, W[0], as_[0], ad_[0], hbA, aS, aD);
  aggregate_kernel<128><<<AGG, 256, 0, stream>>>(
      hbA, aS, aD, final_, rowp2, scal, 0, bb[0], hbB);

  // layer 2: MFMA 128->128
  gemm_mfma_kernel<128><<<dim3((N_NODES+63)/64,2), 256, 0, stream>>>(
      hbB, W[1], as_[1], ad_[1], hbA, aS, aD);
  aggregate_kernel<128><<<AGG, 256, 0, stream>>>(
      hbA, aS, aD, final_, rowp2, scal, 1, bb[1], hbB);

  // layer 3: MFMA 128->64
  gemm_mfma_kernel<64><<<dim3((N_NODES+63)/64,2), 256, 0, stream>>>(
      hbB, W[2], as_[2], ad_[2], hbA, aS, aD);
  aggregate_kernel<64><<<AGG, 256, 0, stream>>>(
      hbA, aS, aD, final_, rowp2, scal, 2, bb[2], hbB);

  pool_final_kernel<<<2*N_GRAPHS, 256, 0, stream>>>(
      hbB, gb, xn1, xn2, linW, linb, out);
}